// Round 6
// baseline (174.977 us; speedup 1.0000x reference)
//
#include <hip/hip_runtime.h>
#include <hip/hip_bf16.h>

// ===== DIAGNOSTIC ROUND =====
// Exact R2 structure (best: 57.3us), but each kernel repeats its full work
// 4x (identical results each rep; opaque_zero defeats load caching/DCE).
// Purpose: push both kernels above the harness's 57us fill dispatches so
// rocprof top-5 finally shows OUR per-kernel counters. dur/4 ~ true dur.

constexpr int D_IN  = 256;
constexpr int D_OUT = 64;
constexpr int WT_LD = D_IN + 8;

typedef short  s8v  __attribute__((ext_vector_type(8)));
typedef __bf16 bf8v __attribute__((ext_vector_type(8)));
typedef float  f32x4 __attribute__((ext_vector_type(4)));
typedef unsigned short us8v __attribute__((ext_vector_type(8)));

union BF8 { bf8v b; s8v s; };

__device__ __forceinline__ int opaque_zero() {
    int z;
    asm volatile("v_mov_b32 %0, 0" : "=v"(z));
    return z;
}

__global__ __launch_bounds__(256) void gemm_bf16_kernel(
    const float* __restrict__ X, const float* __restrict__ W,
    const float* __restrict__ deg, unsigned short* __restrict__ Xp, int n)
{
    __shared__ __bf16 Wt[D_OUT][WT_LD];

    const int tid = threadIdx.x;

    #pragma unroll
    for (int i = 0; i < 16; ++i) {
        const int f4 = tid + i * 256;
        const int k  = f4 >> 4;
        const int c4 = (f4 & 15) * 4;
        const float4 w = *reinterpret_cast<const float4*>(&W[(size_t)k * D_OUT + c4]);
        Wt[c4 + 0][k] = (__bf16)w.x;
        Wt[c4 + 1][k] = (__bf16)w.y;
        Wt[c4 + 2][k] = (__bf16)w.z;
        Wt[c4 + 3][k] = (__bf16)w.w;
    }
    __syncthreads();

    const int wid  = tid >> 6;
    const int lane = tid & 63;
    const int lrow = lane & 15;
    const int kgrp = lane >> 4;

    const int row0 = blockIdx.x * 64 + wid * 16;
    if (row0 >= n) return;
    const int grow = row0 + lrow;
    const int xr   = grow < n ? grow : n - 1;

    const __bf16* wt0 = &Wt[lrow][kgrp * 8];

    for (int rep = 0; rep < 4; ++rep) {
        // opaque zero: forces X reloads each rep (no cross-rep caching)
        const float* xrow = X + (size_t)xr * D_IN + kgrp * 8 + opaque_zero();

        f32x4 acc[4] = {};

        #pragma unroll
        for (int ks = 0; ks < 8; ++ks) {
            const float4 x0 = *reinterpret_cast<const float4*>(xrow + ks * 32);
            const float4 x1 = *reinterpret_cast<const float4*>(xrow + ks * 32 + 4);
            BF8 xf;
            xf.b[0] = (__bf16)x0.x; xf.b[1] = (__bf16)x0.y;
            xf.b[2] = (__bf16)x0.z; xf.b[3] = (__bf16)x0.w;
            xf.b[4] = (__bf16)x1.x; xf.b[5] = (__bf16)x1.y;
            xf.b[6] = (__bf16)x1.z; xf.b[7] = (__bf16)x1.w;

            #pragma unroll
            for (int f = 0; f < 4; ++f) {
                const s8v wf = *reinterpret_cast<const s8v*>(
                    wt0 + (size_t)f * 16 * WT_LD + ks * 32);
                acc[f] = __builtin_amdgcn_mfma_f32_16x16x32_bf16(wf, xf.s, acc[f], 0, 0, 0);
            }
        }

        if (grow < n) {
            const float d = deg[grow];
            #pragma unroll
            for (int f = 0; f < 4; ++f) {
                ushort4 v;
                __bf16 b0 = (__bf16)(acc[f][0] * d);
                __bf16 b1 = (__bf16)(acc[f][1] * d);
                __bf16 b2 = (__bf16)(acc[f][2] * d);
                __bf16 b3 = (__bf16)(acc[f][3] * d);
                v.x = *reinterpret_cast<unsigned short*>(&b0);
                v.y = *reinterpret_cast<unsigned short*>(&b1);
                v.z = *reinterpret_cast<unsigned short*>(&b2);
                v.w = *reinterpret_cast<unsigned short*>(&b3);
                *reinterpret_cast<ushort4*>(
                    &Xp[(size_t)grow * D_OUT + f * 16 + kgrp * 4]) = v;
            }
        }
    }
}

__global__ __launch_bounds__(256) void agg_kernel(
    const unsigned short* __restrict__ Xp, const int* __restrict__ rp,
    const int* __restrict__ ci, const float* __restrict__ deg,
    float* __restrict__ out, int n)
{
    const int node = blockIdx.x * 32 + (threadIdx.x >> 3);
    if (node >= n) return;
    const int c8 = (threadIdx.x & 7) * 8;

    const float d = deg[node];

    for (int rep = 0; rep < 4; ++rep) {
        // opaque zero: forces idx + gather reloads each rep
        const int e0 = rp[node] + opaque_zero();
        const int e1 = rp[node + 1];
        const int m  = e1 - e0;

        float acc[8] = {};

        if (m == 16 && (e0 & 3) == 0) {
            int4 i4[4];
            #pragma unroll
            for (int b = 0; b < 4; ++b)
                i4[b] = *reinterpret_cast<const int4*>(&ci[e0 + b * 4]);
            const int idx[16] = { i4[0].x, i4[0].y, i4[0].z, i4[0].w,
                                  i4[1].x, i4[1].y, i4[1].z, i4[1].w,
                                  i4[2].x, i4[2].y, i4[2].z, i4[2].w,
                                  i4[3].x, i4[3].y, i4[3].z, i4[3].w };
            us8v v[16];
            #pragma unroll
            for (int j = 0; j < 16; ++j)
                v[j] = *reinterpret_cast<const us8v*>(&Xp[(size_t)idx[j] * D_OUT + c8]);
            #pragma unroll
            for (int j = 0; j < 16; ++j) {
                #pragma unroll
                for (int k = 0; k < 8; ++k)
                    acc[k] += __uint_as_float((unsigned)v[j][k] << 16);
            }
        } else {
            for (int e = e0; e < e1; ++e) {
                const us8v v = *reinterpret_cast<const us8v*>(&Xp[(size_t)ci[e] * D_OUT + c8]);
                #pragma unroll
                for (int k = 0; k < 8; ++k)
                    acc[k] += __uint_as_float((unsigned)v[k] << 16);
            }
        }

        float* op = out + (size_t)node * D_OUT + c8;
        *reinterpret_cast<float4*>(op)     = make_float4(acc[0]*d, acc[1]*d, acc[2]*d, acc[3]*d);
        *reinterpret_cast<float4*>(op + 4) = make_float4(acc[4]*d, acc[5]*d, acc[6]*d, acc[7]*d);
    }
}

extern "C" void kernel_launch(void* const* d_in, const int* in_sizes, int n_in,
                              void* d_out, int out_size, void* d_ws, size_t ws_size,
                              hipStream_t stream)
{
    const float* X   = (const float*)d_in[0];
    const float* W   = (const float*)d_in[1];
    const int*   rp  = (const int*)d_in[2];
    const int*   ci  = (const int*)d_in[3];
    const float* deg = (const float*)d_in[4];
    float* out = (float*)d_out;
    unsigned short* Xp = (unsigned short*)d_ws;

    const int n = in_sizes[4];

    const int gemm_blocks = (n + 63) / 64;
    gemm_bf16_kernel<<<gemm_blocks, 256, 0, stream>>>(X, W, deg, Xp, n);

    const int agg_blocks = (n + 31) / 32;
    agg_kernel<<<agg_blocks, 256, 0, stream>>>(Xp, rp, ci, deg, out, n);
}

// Round 7
// 56.144 us; speedup vs baseline: 3.1166x; 3.1166x over previous
//
#include <hip/hip_runtime.h>
#include <hip/hip_bf16.h>

// GCN: out[i] = deg_i * sum_{j in N(i)} deg_j * (X@W)[j]
// K1 gemm: R2 structure (W transposed->LDS inline, operand-swapped MFMA,
//          fused deg_j scale, bf16 Xp). CHANGE: X loads software-pipelined
//          in two 8-load halves -> 2 latency exposures/tile instead of 8.
// K2 agg:  exact R2 agg (measured ~25us, at random-gather ceiling).

constexpr int D_IN  = 256;
constexpr int D_OUT = 64;
constexpr int WT_LD = D_IN + 8;

typedef short  s8v  __attribute__((ext_vector_type(8)));
typedef __bf16 bf8v __attribute__((ext_vector_type(8)));
typedef float  f32x4 __attribute__((ext_vector_type(4)));
typedef unsigned short us8v __attribute__((ext_vector_type(8)));

union BF8 { bf8v b; s8v s; };

__global__ __launch_bounds__(256) void gemm_bf16_kernel(
    const float* __restrict__ X, const float* __restrict__ W,
    const float* __restrict__ deg, unsigned short* __restrict__ Xp, int n)
{
    __shared__ __bf16 Wt[D_OUT][WT_LD];

    const int tid = threadIdx.x;

    #pragma unroll
    for (int i = 0; i < 16; ++i) {
        const int f4 = tid + i * 256;
        const int k  = f4 >> 4;
        const int c4 = (f4 & 15) * 4;
        const float4 w = *reinterpret_cast<const float4*>(&W[(size_t)k * D_OUT + c4]);
        Wt[c4 + 0][k] = (__bf16)w.x;
        Wt[c4 + 1][k] = (__bf16)w.y;
        Wt[c4 + 2][k] = (__bf16)w.z;
        Wt[c4 + 3][k] = (__bf16)w.w;
    }
    __syncthreads();

    const int wid  = tid >> 6;
    const int lane = tid & 63;
    const int lrow = lane & 15;
    const int kgrp = lane >> 4;

    const int row0 = blockIdx.x * 64 + wid * 16;
    if (row0 >= n) return;
    const int grow = row0 + lrow;
    const int xr   = grow < n ? grow : n - 1;

    const __bf16* wt0 = &Wt[lrow][kgrp * 8];
    const float* xrow = X + (size_t)xr * D_IN + kgrp * 8;

    // ---- software pipeline: two 8-load halves ----
    float4 xa[8], xb[8];
    #pragma unroll
    for (int k = 0; k < 4; ++k) {            // issue half A (ks 0..3)
        xa[2 * k]     = *reinterpret_cast<const float4*>(xrow + k * 32);
        xa[2 * k + 1] = *reinterpret_cast<const float4*>(xrow + k * 32 + 4);
    }
    #pragma unroll
    for (int k = 0; k < 4; ++k) {            // issue half B (ks 4..7)
        xb[2 * k]     = *reinterpret_cast<const float4*>(xrow + (k + 4) * 32);
        xb[2 * k + 1] = *reinterpret_cast<const float4*>(xrow + (k + 4) * 32 + 4);
    }

    f32x4 acc[4] = {};

    #pragma unroll
    for (int ks = 0; ks < 4; ++ks) {         // consume A (B in flight)
        BF8 xf;
        const float4 x0 = xa[2 * ks];
        const float4 x1 = xa[2 * ks + 1];
        xf.b[0] = (__bf16)x0.x; xf.b[1] = (__bf16)x0.y;
        xf.b[2] = (__bf16)x0.z; xf.b[3] = (__bf16)x0.w;
        xf.b[4] = (__bf16)x1.x; xf.b[5] = (__bf16)x1.y;
        xf.b[6] = (__bf16)x1.z; xf.b[7] = (__bf16)x1.w;
        #pragma unroll
        for (int f = 0; f < 4; ++f) {
            const s8v wf = *reinterpret_cast<const s8v*>(
                wt0 + (size_t)f * 16 * WT_LD + ks * 32);
            acc[f] = __builtin_amdgcn_mfma_f32_16x16x32_bf16(wf, xf.s, acc[f], 0, 0, 0);
        }
    }
    #pragma unroll
    for (int ks = 4; ks < 8; ++ks) {         // consume B
        BF8 xf;
        const float4 x0 = xb[2 * (ks - 4)];
        const float4 x1 = xb[2 * (ks - 4) + 1];
        xf.b[0] = (__bf16)x0.x; xf.b[1] = (__bf16)x0.y;
        xf.b[2] = (__bf16)x0.z; xf.b[3] = (__bf16)x0.w;
        xf.b[4] = (__bf16)x1.x; xf.b[5] = (__bf16)x1.y;
        xf.b[6] = (__bf16)x1.z; xf.b[7] = (__bf16)x1.w;
        #pragma unroll
        for (int f = 0; f < 4; ++f) {
            const s8v wf = *reinterpret_cast<const s8v*>(
                wt0 + (size_t)f * 16 * WT_LD + ks * 32);
            acc[f] = __builtin_amdgcn_mfma_f32_16x16x32_bf16(wf, xf.s, acc[f], 0, 0, 0);
        }
    }

    if (grow < n) {
        const float d = deg[grow];
        #pragma unroll
        for (int f = 0; f < 4; ++f) {
            ushort4 v;
            __bf16 b0 = (__bf16)(acc[f][0] * d);
            __bf16 b1 = (__bf16)(acc[f][1] * d);
            __bf16 b2 = (__bf16)(acc[f][2] * d);
            __bf16 b3 = (__bf16)(acc[f][3] * d);
            v.x = *reinterpret_cast<unsigned short*>(&b0);
            v.y = *reinterpret_cast<unsigned short*>(&b1);
            v.z = *reinterpret_cast<unsigned short*>(&b2);
            v.w = *reinterpret_cast<unsigned short*>(&b3);
            *reinterpret_cast<ushort4*>(
                &Xp[(size_t)grow * D_OUT + f * 16 + kgrp * 4]) = v;
        }
    }
}

__global__ __launch_bounds__(256) void agg_kernel(
    const unsigned short* __restrict__ Xp, const int* __restrict__ rp,
    const int* __restrict__ ci, const float* __restrict__ deg,
    float* __restrict__ out, int n)
{
    const int node = blockIdx.x * 32 + (threadIdx.x >> 3);
    if (node >= n) return;
    const int c8 = (threadIdx.x & 7) * 8;

    const int e0 = rp[node];
    const int e1 = rp[node + 1];
    const int m  = e1 - e0;
    const float d = deg[node];

    float acc[8] = {};

    if (m == 16 && (e0 & 3) == 0) {
        int4 i4[4];
        #pragma unroll
        for (int b = 0; b < 4; ++b)
            i4[b] = *reinterpret_cast<const int4*>(&ci[e0 + b * 4]);
        const int idx[16] = { i4[0].x, i4[0].y, i4[0].z, i4[0].w,
                              i4[1].x, i4[1].y, i4[1].z, i4[1].w,
                              i4[2].x, i4[2].y, i4[2].z, i4[2].w,
                              i4[3].x, i4[3].y, i4[3].z, i4[3].w };
        us8v v[16];
        #pragma unroll
        for (int j = 0; j < 16; ++j)
            v[j] = *reinterpret_cast<const us8v*>(&Xp[(size_t)idx[j] * D_OUT + c8]);
        #pragma unroll
        for (int j = 0; j < 16; ++j) {
            #pragma unroll
            for (int k = 0; k < 8; ++k)
                acc[k] += __uint_as_float((unsigned)v[j][k] << 16);
        }
    } else {
        for (int e = e0; e < e1; ++e) {
            const us8v v = *reinterpret_cast<const us8v*>(&Xp[(size_t)ci[e] * D_OUT + c8]);
            #pragma unroll
            for (int k = 0; k < 8; ++k)
                acc[k] += __uint_as_float((unsigned)v[k] << 16);
        }
    }

    float* op = out + (size_t)node * D_OUT + c8;
    *reinterpret_cast<float4*>(op)     = make_float4(acc[0]*d, acc[1]*d, acc[2]*d, acc[3]*d);
    *reinterpret_cast<float4*>(op + 4) = make_float4(acc[4]*d, acc[5]*d, acc[6]*d, acc[7]*d);
}

extern "C" void kernel_launch(void* const* d_in, const int* in_sizes, int n_in,
                              void* d_out, int out_size, void* d_ws, size_t ws_size,
                              hipStream_t stream)
{
    const float* X   = (const float*)d_in[0];
    const float* W   = (const float*)d_in[1];
    const int*   rp  = (const int*)d_in[2];
    const int*   ci  = (const int*)d_in[3];
    const float* deg = (const float*)d_in[4];
    float* out = (float*)d_out;
    unsigned short* Xp = (unsigned short*)d_ws;

    const int n = in_sizes[4];

    const int gemm_blocks = (n + 63) / 64;
    gemm_bf16_kernel<<<gemm_blocks, 256, 0, stream>>>(X, W, deg, Xp, n);

    const int agg_blocks = (n + 31) / 32;
    agg_kernel<<<agg_blocks, 256, 0, stream>>>(Xp, rp, ci, deg, out, n);
}